// Round 1
// baseline (2641.830 us; speedup 1.0000x reference)
//
#include <hip/hip_runtime.h>
#include <hip/hip_bf16.h>

#define T_TOK 8192
#define HID 2048
#define FFN_ 8192
#define NE 8
#define MAXROWS 17408   // 16384 + 8*128 padding
#define BM 128
#define BN 128
#define BK 32

typedef __attribute__((ext_vector_type(8))) short bf16x8;
typedef __attribute__((ext_vector_type(4))) float f32x4;
typedef __attribute__((ext_vector_type(8))) unsigned short u16x8;

__device__ __forceinline__ unsigned short f2bf(float f) {
  unsigned int u = __float_as_uint(f);
  u += 0x7fffu + ((u >> 16) & 1u);   // RNE
  return (unsigned short)(u >> 16);
}
__device__ __forceinline__ float bf2f(unsigned short h) {
  return __uint_as_float(((unsigned int)h) << 16);
}

__device__ __forceinline__ void gload_lds16(const ushort* g, ushort* l) {
  __builtin_amdgcn_global_load_lds(
      (const __attribute__((address_space(1))) unsigned int*)g,
      (__attribute__((address_space(3))) unsigned int*)l, 16, 0, 0);
}

// ---------------- router: one wave per token ----------------
__global__ __launch_bounds__(256) void router_kernel(
    const float* __restrict__ x, const float* __restrict__ gw,
    int* __restrict__ topk_idx, float* __restrict__ topk_w, int* __restrict__ counts)
{
  int lane = threadIdx.x & 63;
  int w = threadIdx.x >> 6;
  int t = blockIdx.x * 4 + w;
  const float* xr = x + (size_t)t * HID;
  float acc[NE];
#pragma unroll
  for (int e = 0; e < NE; ++e) acc[e] = 0.f;
  for (int h = lane; h < HID; h += 64) {
    float xv = xr[h];
#pragma unroll
    for (int e = 0; e < NE; ++e) acc[e] = fmaf(xv, gw[e * HID + h], acc[e]);
  }
#pragma unroll
  for (int e = 0; e < NE; ++e) {
#pragma unroll
    for (int s = 32; s > 0; s >>= 1) acc[e] += __shfl_xor(acc[e], s);
  }
  if (lane == 0) {
    int i0 = 0; float v0 = acc[0];
#pragma unroll
    for (int e = 1; e < NE; ++e) { if (acc[e] > v0) { v0 = acc[e]; i0 = e; } }
    int i1 = -1; float v1 = -3.4e38f;
#pragma unroll
    for (int e = 0; e < NE; ++e) { if (e != i0 && acc[e] > v1) { v1 = acc[e]; i1 = e; } }
    // renormalized top-2 softmax weights == 2-way softmax of the two logits
    float r = __expf(v1 - v0);
    float w0 = 1.f / (1.f + r);
    float w1 = r * w0;
    topk_idx[2 * t] = i0; topk_idx[2 * t + 1] = i1;
    topk_w[2 * t] = w0;   topk_w[2 * t + 1] = w1;
    atomicAdd(&counts[i0], 1);
    atomicAdd(&counts[i1], 1);
  }
}

__global__ void offsets_kernel(const int* __restrict__ counts, int* __restrict__ offs) {
  if (threadIdx.x == 0 && blockIdx.x == 0) {
    int o = 0;
#pragma unroll
    for (int e = 0; e < NE; ++e) { offs[e] = o; o += (counts[e] + BM - 1) & ~(BM - 1); }
    offs[NE] = o;
  }
}

__global__ __launch_bounds__(256) void scatter_kernel(
    const int* __restrict__ topk_idx, const float* __restrict__ topk_w,
    const int* __restrict__ offs, int* __restrict__ cursors,
    int* __restrict__ slot_token, float* __restrict__ slot_w, int* __restrict__ token_slot)
{
  int t = blockIdx.x * blockDim.x + threadIdx.x;
  if (t >= T_TOK) return;
#pragma unroll
  for (int k = 0; k < 2; ++k) {
    int e = topk_idx[2 * t + k];
    int pos = atomicAdd(&cursors[e], 1);
    int slot = offs[e] + pos;
    slot_token[slot] = t;
    slot_w[slot] = topk_w[2 * t + k];
    token_slot[2 * t + k] = slot;
  }
}

// gather token rows into bf16, one block per slot row
__global__ __launch_bounds__(256) void gather_kernel(
    const float* __restrict__ x, const int* __restrict__ slot_token, ushort* __restrict__ Xg)
{
  int row = blockIdx.x;
  int tok = slot_token[row];
  ushort* dst = Xg + (size_t)row * HID + threadIdx.x * 8;
  if (tok < 0) {
    u16x8 z = {0, 0, 0, 0, 0, 0, 0, 0};
    *(u16x8*)dst = z;
  } else {
    const float* s = x + (size_t)tok * HID + threadIdx.x * 8;
    float4 a = *(const float4*)s;
    float4 b = *(const float4*)(s + 4);
    u16x8 v;
    v[0] = f2bf(a.x); v[1] = f2bf(a.y); v[2] = f2bf(a.z); v[3] = f2bf(a.w);
    v[4] = f2bf(b.x); v[5] = f2bf(b.y); v[6] = f2bf(b.z); v[7] = f2bf(b.w);
    *(u16x8*)dst = v;
  }
}

// fp32 [E][R][C] -> bf16 [E][C][R]
__global__ __launch_bounds__(256) void transpose_convert_kernel(
    const float* __restrict__ src, ushort* __restrict__ dst, int R, int C)
{
  __shared__ float tile[64][65];
  int e = blockIdx.z;
  const float* s = src + (size_t)e * R * C;
  ushort* d = dst + (size_t)e * R * C;
  int r0 = blockIdx.y << 6, c0 = blockIdx.x << 6;
  int t = threadIdx.x;
#pragma unroll
  for (int i = 0; i < 4; ++i) {
    int idx = i * 256 + t;
    int row = idx >> 4;
    int c4 = (idx & 15) << 2;
    float4 v = *(const float4*)&s[(size_t)(r0 + row) * C + (c0 + c4)];
    tile[row][c4 + 0] = v.x; tile[row][c4 + 1] = v.y;
    tile[row][c4 + 2] = v.z; tile[row][c4 + 3] = v.w;
  }
  __syncthreads();
#pragma unroll
  for (int i = 0; i < 8; ++i) {
    int idx = (i * 256 + t) * 2;
    int orow = idx >> 6;        // dst row within tile (= src col)
    int ocol = idx & 63;        // dst col (= src row), even
    ushort2 p;
    p.x = f2bf(tile[ocol][orow]);
    p.y = f2bf(tile[ocol + 1][orow]);
    *(ushort2*)&d[(size_t)(c0 + orow) * R + (r0 + ocol)] = p;
  }
}

// ---------------- GEMM: C[row][col] = A[row][:] . Bt[col][:]  (both K-contiguous) ----------
// EPI 0: C = gelu(acc + bias[e][col])            -> Hb
// EPI 1: C = (acc + bias[e][col]) * slot_w[row]  -> Ypair
template <int EPI>
__global__ __launch_bounds__(256) void gemm_kernel(
    const ushort* __restrict__ A, const ushort* __restrict__ Bt,
    const float* __restrict__ bias, ushort* __restrict__ Cout,
    const float* __restrict__ slot_w, const int* __restrict__ offs,
    int K, int N)
{
  __shared__ ushort As[BM * BK];
  __shared__ ushort Bs[BN * BK];

  int tid = threadIdx.x;
  int rb = blockIdx.y, cb = blockIdx.x;
  int total = offs[NE];
  int row0 = rb * BM;
  if (row0 >= total) return;
  int e = 0;
#pragma unroll
  for (int i = 1; i < NE; ++i) e += (row0 >= offs[i]) ? 1 : 0;

  const ushort* Ag = A + (size_t)row0 * K;
  const ushort* Bg = Bt + ((size_t)e * N + (size_t)cb * BN) * K;

  int ar = tid >> 2;               // 0..63
  int ak = (tid & 3) << 3;         // 0,8,16,24
  const ushort* agp0 = Ag + (size_t)ar * K + ak;
  const ushort* agp1 = Ag + (size_t)(ar + 64) * K + ak;
  const ushort* bgp0 = Bg + (size_t)ar * K + ak;
  const ushort* bgp1 = Bg + (size_t)(ar + 64) * K + ak;
  ushort* asl0 = As + tid * 8;
  ushort* asl1 = As + 2048 + tid * 8;
  ushort* bsl0 = Bs + tid * 8;
  ushort* bsl1 = Bs + 2048 + tid * 8;

  int lane = tid & 63;
  int wid = tid >> 6;
  int wr = wid >> 1, wc = wid & 1;
  int lrow = lane & 15;
  int lkb = (lane >> 4) << 3;
  const ushort* Asf = As + (wr * 64 + lrow) * BK + lkb;
  const ushort* Bsf = Bs + (wc * 64 + lrow) * BK + lkb;

  f32x4 acc[4][4] = {};

  for (int k0 = 0; k0 < K; k0 += BK) {
    gload_lds16(agp0 + k0, asl0);
    gload_lds16(agp1 + k0, asl1);
    gload_lds16(bgp0 + k0, bsl0);
    gload_lds16(bgp1 + k0, bsl1);
    __syncthreads();   // drains vmcnt -> LDS valid
    bf16x8 a[4], b[4];
#pragma unroll
    for (int m = 0; m < 4; ++m) a[m] = *(const bf16x8*)(Asf + m * 16 * BK);
#pragma unroll
    for (int n = 0; n < 4; ++n) b[n] = *(const bf16x8*)(Bsf + n * 16 * BK);
#pragma unroll
    for (int m = 0; m < 4; ++m)
#pragma unroll
      for (int n = 0; n < 4; ++n)
        acc[m][n] = __builtin_amdgcn_mfma_f32_16x16x32_bf16(a[m], b[n], acc[m][n], 0, 0, 0);
    __syncthreads();   // reads done before next stage
  }

  int colbase = cb * BN + wc * 64;
  int rowbase = row0 + wr * 64;
#pragma unroll
  for (int n = 0; n < 4; ++n) {
    int gc = colbase + n * 16 + lrow;
    float bv = bias[(size_t)e * N + gc];
#pragma unroll
    for (int m = 0; m < 4; ++m) {
      int gr = rowbase + m * 16 + ((lane >> 4) << 2);
#pragma unroll
      for (int i = 0; i < 4; ++i) {
        float v = acc[m][n][i] + bv;
        if (EPI == 0) {
          v = 0.5f * v * (1.f + erff(v * 0.70710678118654752f));
        } else {
          v *= slot_w[gr + i];
        }
        Cout[(size_t)(gr + i) * N + gc] = f2bf(v);
      }
    }
  }
}

// out = x + Y[slot0] + Y[slot1]
__global__ __launch_bounds__(256) void combine_kernel(
    const float* __restrict__ x, const ushort* __restrict__ Yp,
    const int* __restrict__ token_slot, float* __restrict__ out)
{
  int t = blockIdx.x;
  int s0 = token_slot[2 * t], s1 = token_slot[2 * t + 1];
  int c = threadIdx.x * 8;
  const float* xr = x + (size_t)t * HID + c;
  u16x8 y0 = *(const u16x8*)&Yp[(size_t)s0 * HID + c];
  u16x8 y1 = *(const u16x8*)&Yp[(size_t)s1 * HID + c];
  float4 xa = *(const float4*)xr;
  float4 xb = *(const float4*)(xr + 4);
  float4 oa, ob;
  oa.x = xa.x + bf2f(y0[0]) + bf2f(y1[0]);
  oa.y = xa.y + bf2f(y0[1]) + bf2f(y1[1]);
  oa.z = xa.z + bf2f(y0[2]) + bf2f(y1[2]);
  oa.w = xa.w + bf2f(y0[3]) + bf2f(y1[3]);
  ob.x = xb.x + bf2f(y0[4]) + bf2f(y1[4]);
  ob.y = xb.y + bf2f(y0[5]) + bf2f(y1[5]);
  ob.z = xb.z + bf2f(y0[6]) + bf2f(y1[6]);
  ob.w = xb.w + bf2f(y0[7]) + bf2f(y1[7]);
  float* orow = out + (size_t)t * HID + c;
  *(float4*)orow = oa;
  *(float4*)(orow + 4) = ob;
}

extern "C" void kernel_launch(void* const* d_in, const int* in_sizes, int n_in,
                              void* d_out, int out_size, void* d_ws, size_t ws_size,
                              hipStream_t stream)
{
  const float* x  = (const float*)d_in[0];
  const float* gw = (const float*)d_in[1];
  const float* w1 = (const float*)d_in[2];
  const float* b1 = (const float*)d_in[3];
  const float* w2 = (const float*)d_in[4];
  const float* b2 = (const float*)d_in[5];
  float* out = (float*)d_out;

  char* ws = (char*)d_ws;
  // layout (bytes)
  ushort* w1t = (ushort*)(ws + 0);            // [E][F][H] bf16: 268,435,456
  ushort* w2t = (ushort*)(ws + 268435456);    // [E][H][F] bf16: 268,435,456
  ushort* Hb  = (ushort*)(ws + 536870912);    // [MAXROWS][F] bf16: 285,212,672
  ushort* Xg  = (ushort*)(ws + 822083584);    // [MAXROWS][H] bf16: 71,303,168
  ushort* Yp  = Xg;                           // Ypair overlays Xg (Xg dead after gemm1)
  char* sm = ws + 893386752;
  int*   slot_token = (int*)(sm);             // 69,632
  float* slot_w     = (float*)(sm + 69632);   // 69,632
  int*   token_slot = (int*)(sm + 139264);    // 65,536
  int*   topk_idx   = (int*)(sm + 204800);    // 65,536
  float* topk_w     = (float*)(sm + 270336);  // 65,536
  int*   counts     = (int*)(sm + 335872);    // 64
  int*   cursors    = (int*)(sm + 335936);    // 64
  int*   offs       = (int*)(sm + 336000);    // 64 (E+1 ints)

  hipMemsetAsync(counts, 0, 128, stream);               // counts + cursors
  hipMemsetAsync(slot_token, 0xFF, MAXROWS * 4, stream); // -1 padding

  router_kernel<<<dim3(T_TOK / 4), dim3(256), 0, stream>>>(x, gw, topk_idx, topk_w, counts);
  offsets_kernel<<<dim3(1), dim3(64), 0, stream>>>(counts, offs);
  scatter_kernel<<<dim3(T_TOK / 256), dim3(256), 0, stream>>>(
      topk_idx, topk_w, offs, cursors, slot_token, slot_w, token_slot);
  gather_kernel<<<dim3(MAXROWS), dim3(256), 0, stream>>>(x, slot_token, Xg);

  // weights: fp32 [R][C] -> bf16 [C][R] per expert
  transpose_convert_kernel<<<dim3(FFN_ / 64, HID / 64, NE), dim3(256), 0, stream>>>(
      w1, w1t, HID, FFN_);
  transpose_convert_kernel<<<dim3(HID / 64, FFN_ / 64, NE), dim3(256), 0, stream>>>(
      w2, w2t, FFN_, HID);

  gemm_kernel<0><<<dim3(FFN_ / BN, MAXROWS / BM), dim3(256), 0, stream>>>(
      Xg, w1t, b1, Hb, nullptr, offs, HID, FFN_);
  gemm_kernel<1><<<dim3(HID / BN, MAXROWS / BM), dim3(256), 0, stream>>>(
      Hb, w2t, b2, Yp, slot_w, offs, FFN_, HID);

  combine_kernel<<<dim3(T_TOK), dim3(256), 0, stream>>>(x, Yp, token_slot, out);
}

// Round 2
// 2239.353 us; speedup vs baseline: 1.1797x; 1.1797x over previous
//
#include <hip/hip_runtime.h>
#include <hip/hip_bf16.h>

#define T_TOK 8192
#define HID 2048
#define FFN_ 8192
#define NE 8
#define MAXROWS 17408   // 16384 + 8*128 padding
#define BM 128
#define BN2 256
#define BK2 64

typedef __attribute__((ext_vector_type(8))) short bf16x8;
typedef __attribute__((ext_vector_type(4))) float f32x4;
typedef __attribute__((ext_vector_type(8))) unsigned short u16x8;

__device__ __forceinline__ unsigned short f2bf(float f) {
  unsigned int u = __float_as_uint(f);
  u += 0x7fffu + ((u >> 16) & 1u);   // RNE
  return (unsigned short)(u >> 16);
}
__device__ __forceinline__ float bf2f(unsigned short h) {
  return __uint_as_float(((unsigned int)h) << 16);
}

__device__ __forceinline__ void gload_lds16(const ushort* g, ushort* l) {
  __builtin_amdgcn_global_load_lds(
      (const __attribute__((address_space(1))) unsigned int*)g,
      (__attribute__((address_space(3))) unsigned int*)l, 16, 0, 0);
}

// ---------------- router: one wave per token ----------------
__global__ __launch_bounds__(256) void router_kernel(
    const float* __restrict__ x, const float* __restrict__ gw,
    int* __restrict__ topk_idx, float* __restrict__ topk_w, int* __restrict__ counts)
{
  int lane = threadIdx.x & 63;
  int w = threadIdx.x >> 6;
  int t = blockIdx.x * 4 + w;
  const float* xr = x + (size_t)t * HID;
  float acc[NE];
#pragma unroll
  for (int e = 0; e < NE; ++e) acc[e] = 0.f;
  for (int h = lane; h < HID; h += 64) {
    float xv = xr[h];
#pragma unroll
    for (int e = 0; e < NE; ++e) acc[e] = fmaf(xv, gw[e * HID + h], acc[e]);
  }
#pragma unroll
  for (int e = 0; e < NE; ++e) {
#pragma unroll
    for (int s = 32; s > 0; s >>= 1) acc[e] += __shfl_xor(acc[e], s);
  }
  if (lane == 0) {
    int i0 = 0; float v0 = acc[0];
#pragma unroll
    for (int e = 1; e < NE; ++e) { if (acc[e] > v0) { v0 = acc[e]; i0 = e; } }
    int i1 = -1; float v1 = -3.4e38f;
#pragma unroll
    for (int e = 0; e < NE; ++e) { if (e != i0 && acc[e] > v1) { v1 = acc[e]; i1 = e; } }
    float r = __expf(v1 - v0);
    float w0 = 1.f / (1.f + r);
    float w1 = r * w0;
    topk_idx[2 * t] = i0; topk_idx[2 * t + 1] = i1;
    topk_w[2 * t] = w0;   topk_w[2 * t + 1] = w1;
    atomicAdd(&counts[i0], 1);
    atomicAdd(&counts[i1], 1);
  }
}

__global__ void offsets_kernel(const int* __restrict__ counts, int* __restrict__ offs) {
  if (threadIdx.x == 0 && blockIdx.x == 0) {
    int o = 0;
#pragma unroll
    for (int e = 0; e < NE; ++e) { offs[e] = o; o += (counts[e] + BM - 1) & ~(BM - 1); }
    offs[NE] = o;
  }
}

__global__ __launch_bounds__(256) void scatter_kernel(
    const int* __restrict__ topk_idx, const float* __restrict__ topk_w,
    const int* __restrict__ offs, int* __restrict__ cursors,
    int* __restrict__ slot_token, float* __restrict__ slot_w, int* __restrict__ token_slot)
{
  int t = blockIdx.x * blockDim.x + threadIdx.x;
  if (t >= T_TOK) return;
#pragma unroll
  for (int k = 0; k < 2; ++k) {
    int e = topk_idx[2 * t + k];
    int pos = atomicAdd(&cursors[e], 1);
    int slot = offs[e] + pos;
    slot_token[slot] = t;
    slot_w[slot] = topk_w[2 * t + k];
    token_slot[2 * t + k] = slot;
  }
}

// gather token rows into bf16, one block per slot row
__global__ __launch_bounds__(256) void gather_kernel(
    const float* __restrict__ x, const int* __restrict__ slot_token, ushort* __restrict__ Xg)
{
  int row = blockIdx.x;
  int tok = slot_token[row];
  ushort* dst = Xg + (size_t)row * HID + threadIdx.x * 8;
  if (tok < 0) {
    u16x8 z = {0, 0, 0, 0, 0, 0, 0, 0};
    *(u16x8*)dst = z;
  } else {
    const float* s = x + (size_t)tok * HID + threadIdx.x * 8;
    float4 a = *(const float4*)s;
    float4 b = *(const float4*)(s + 4);
    u16x8 v;
    v[0] = f2bf(a.x); v[1] = f2bf(a.y); v[2] = f2bf(a.z); v[3] = f2bf(a.w);
    v[4] = f2bf(b.x); v[5] = f2bf(b.y); v[6] = f2bf(b.z); v[7] = f2bf(b.w);
    *(u16x8*)dst = v;
  }
}

// fp32 [E][R][C] -> bf16 [E][C][R]
__global__ __launch_bounds__(256) void transpose_convert_kernel(
    const float* __restrict__ src, ushort* __restrict__ dst, int R, int C)
{
  __shared__ float tile[64][65];
  int e = blockIdx.z;
  const float* s = src + (size_t)e * R * C;
  ushort* d = dst + (size_t)e * R * C;
  int r0 = blockIdx.y << 6, c0 = blockIdx.x << 6;
  int t = threadIdx.x;
#pragma unroll
  for (int i = 0; i < 4; ++i) {
    int idx = i * 256 + t;
    int row = idx >> 4;
    int c4 = (idx & 15) << 2;
    float4 v = *(const float4*)&s[(size_t)(r0 + row) * C + (c0 + c4)];
    tile[row][c4 + 0] = v.x; tile[row][c4 + 1] = v.y;
    tile[row][c4 + 2] = v.z; tile[row][c4 + 3] = v.w;
  }
  __syncthreads();
#pragma unroll
  for (int i = 0; i < 8; ++i) {
    int idx = (i * 256 + t) * 2;
    int orow = idx >> 6;
    int ocol = idx & 63;
    ushort2 p;
    p.x = f2bf(tile[ocol][orow]);
    p.y = f2bf(tile[ocol + 1][orow]);
    *(ushort2*)&d[(size_t)(c0 + orow) * R + (r0 + ocol)] = p;
  }
}

// ---------------- GEMM 128x256, BK=64, 8 waves, dbuf LDS + counted vmcnt ----------
// C[row][col] = A[row][:] . Bt[col][:]  (both K-contiguous)
// EPI 0: C = gelu(acc + bias[e][col])            -> Hb
// EPI 1: C = (acc + bias[e][col]) * slot_w[row]  -> Ypair
//
// LDS layout per buffer (ushort units): A tile [128][64] at +0 (8192),
// B tile [256][64] at +8192 (16384). Buffer stride 24576. Total 49152 ushorts = 96 KiB.
// T2 swizzle: logical 16B chunk j of row r lives at physical chunk j^(r&7).
// global_load_lds writes LINEAR; the global source address is pre-swizzled
// (rule 21: linear dest + inverse-swizzled source + swizzled read).

#define STAGE(buf, k0) do {                                                  \
    ushort* _b = lds + (buf) * 24576;                                        \
    gload_lds16(Ag + ga + (size_t)(k0), _b + tid * 8);                       \
    gload_lds16(Ag + ga + (size_t)64 * K + (k0), _b + 4096 + tid * 8);       \
    gload_lds16(Bg + ga + (size_t)(k0), _b + 8192 + tid * 8);                \
    gload_lds16(Bg + ga + (size_t)64 * K + (k0), _b + 12288 + tid * 8);      \
    gload_lds16(Bg + ga + (size_t)128 * K + (k0), _b + 16384 + tid * 8);     \
    gload_lds16(Bg + ga + (size_t)192 * K + (k0), _b + 20480 + tid * 8);     \
  } while (0)

template <int EPI>
__global__ __launch_bounds__(512) void gemm8_kernel(
    const ushort* __restrict__ A, const ushort* __restrict__ Bt,
    const float* __restrict__ bias, ushort* __restrict__ Cout,
    const float* __restrict__ slot_w, const int* __restrict__ offs,
    int K, int N, int gx)
{
  __shared__ ushort lds[49152];

  int tid = threadIdx.x;
  // T1: bijective XCD swizzle on flattened grid (nwg divisible by 8 here)
  int nwg = gridDim.x * gridDim.y;
  int wg = blockIdx.y * gridDim.x + blockIdx.x;
  int cpx = nwg >> 3;
  wg = (wg & 7) * cpx + (wg >> 3);
  int rb = wg / gx, cb = wg - rb * gx;

  int total = offs[NE];
  int row0 = rb * BM;
  if (row0 >= total) return;
  int e = 0;
#pragma unroll
  for (int i = 1; i < NE; ++i) e += (row0 >= offs[i]) ? 1 : 0;

  const ushort* Ag = A + (size_t)row0 * K;
  const ushort* Bg = Bt + ((size_t)e * N + (size_t)cb * BN2) * K;

  // staging source (pre-swizzled): thread t -> physical row srow, chunk t&7;
  // fetch logical chunk j = (t&7) ^ (srow&7)
  int srow = tid >> 3;
  int jc = (tid & 7) ^ (srow & 7);
  size_t ga = (size_t)srow * K + (size_t)jc * 8;

  // fragment read addressing
  int lane = tid & 63;
  int wid = tid >> 6;
  int wr = wid >> 2, wc = wid & 3;      // wave grid 2 (M) x 4 (N)
  int lrow = lane & 15;
  int g = lane >> 4;
  int x7 = lrow & 7;
  int cko0 = ((0 * 4 + g) ^ x7) * 8;    // swizzled chunk offset, kk=0 (ushorts)
  int cko1 = ((1 * 4 + g) ^ x7) * 8;    // kk=1
  int arow0 = wr * 64 + lrow;
  int brow0 = wc * 64 + lrow;

  f32x4 acc[4][4] = {};

  int NT = K >> 6;
  STAGE(0, 0);
  for (int t = 0; t < NT; ++t) {
    int p = t & 1;
    if (t + 1 < NT) {
      STAGE(p ^ 1, (t + 1) << 6);
      asm volatile("s_waitcnt vmcnt(6)" ::: "memory");   // drain tile t only
    } else {
      asm volatile("s_waitcnt vmcnt(0)" ::: "memory");
    }
    __builtin_amdgcn_s_barrier();
    __builtin_amdgcn_sched_barrier(0);

    const ushort* Ab = lds + p * 24576;
    const ushort* Bb = Ab + 8192;
    bf16x8 a0[4], a1[4], b0[4], b1[4];
#pragma unroll
    for (int m = 0; m < 4; ++m) {
      a0[m] = *(const bf16x8*)(Ab + (arow0 + m * 16) * 64 + cko0);
      a1[m] = *(const bf16x8*)(Ab + (arow0 + m * 16) * 64 + cko1);
    }
#pragma unroll
    for (int n = 0; n < 4; ++n) {
      b0[n] = *(const bf16x8*)(Bb + (brow0 + n * 16) * 64 + cko0);
      b1[n] = *(const bf16x8*)(Bb + (brow0 + n * 16) * 64 + cko1);
    }
    __builtin_amdgcn_s_setprio(1);
#pragma unroll
    for (int m = 0; m < 4; ++m)
#pragma unroll
      for (int n = 0; n < 4; ++n)
        acc[m][n] = __builtin_amdgcn_mfma_f32_16x16x32_bf16(a0[m], b0[n], acc[m][n], 0, 0, 0);
#pragma unroll
    for (int m = 0; m < 4; ++m)
#pragma unroll
      for (int n = 0; n < 4; ++n)
        acc[m][n] = __builtin_amdgcn_mfma_f32_16x16x32_bf16(a1[m], b1[n], acc[m][n], 0, 0, 0);
    __builtin_amdgcn_s_setprio(0);
    __builtin_amdgcn_sched_barrier(0);
    __builtin_amdgcn_s_barrier();     // all reads of buf p done -> next iter may stage into it
  }

  int colbase = cb * BN2 + wc * 64;
  int rowbase = row0 + wr * 64;
#pragma unroll
  for (int n = 0; n < 4; ++n) {
    int gc = colbase + n * 16 + lrow;
    float bv = bias[(size_t)e * N + gc];
#pragma unroll
    for (int m = 0; m < 4; ++m) {
      int gr = rowbase + m * 16 + g * 4;
#pragma unroll
      for (int i = 0; i < 4; ++i) {
        float v = acc[m][n][i] + bv;
        if (EPI == 0) {
          v = 0.5f * v * (1.f + erff(v * 0.70710678118654752f));
        } else {
          v *= slot_w[gr + i];
        }
        Cout[(size_t)(gr + i) * N + gc] = f2bf(v);
      }
    }
  }
}

// out = x + Y[slot0] + Y[slot1]
__global__ __launch_bounds__(256) void combine_kernel(
    const float* __restrict__ x, const ushort* __restrict__ Yp,
    const int* __restrict__ token_slot, float* __restrict__ out)
{
  int t = blockIdx.x;
  int s0 = token_slot[2 * t], s1 = token_slot[2 * t + 1];
  int c = threadIdx.x * 8;
  const float* xr = x + (size_t)t * HID + c;
  u16x8 y0 = *(const u16x8*)&Yp[(size_t)s0 * HID + c];
  u16x8 y1 = *(const u16x8*)&Yp[(size_t)s1 * HID + c];
  float4 xa = *(const float4*)xr;
  float4 xb = *(const float4*)(xr + 4);
  float4 oa, ob;
  oa.x = xa.x + bf2f(y0[0]) + bf2f(y1[0]);
  oa.y = xa.y + bf2f(y0[1]) + bf2f(y1[1]);
  oa.z = xa.z + bf2f(y0[2]) + bf2f(y1[2]);
  oa.w = xa.w + bf2f(y0[3]) + bf2f(y1[3]);
  ob.x = xb.x + bf2f(y0[4]) + bf2f(y1[4]);
  ob.y = xb.y + bf2f(y0[5]) + bf2f(y1[5]);
  ob.z = xb.z + bf2f(y0[6]) + bf2f(y1[6]);
  ob.w = xb.w + bf2f(y0[7]) + bf2f(y1[7]);
  float* orow = out + (size_t)t * HID + c;
  *(float4*)orow = oa;
  *(float4*)(orow + 4) = ob;
}

extern "C" void kernel_launch(void* const* d_in, const int* in_sizes, int n_in,
                              void* d_out, int out_size, void* d_ws, size_t ws_size,
                              hipStream_t stream)
{
  const float* x  = (const float*)d_in[0];
  const float* gw = (const float*)d_in[1];
  const float* w1 = (const float*)d_in[2];
  const float* b1 = (const float*)d_in[3];
  const float* w2 = (const float*)d_in[4];
  const float* b2 = (const float*)d_in[5];
  float* out = (float*)d_out;

  char* ws = (char*)d_ws;
  ushort* w1t = (ushort*)(ws + 0);            // [E][F][H] bf16: 268,435,456
  ushort* w2t = (ushort*)(ws + 268435456);    // [E][H][F] bf16: 268,435,456
  ushort* Hb  = (ushort*)(ws + 536870912);    // [MAXROWS][F] bf16: 285,212,672
  ushort* Xg  = (ushort*)(ws + 822083584);    // [MAXROWS][H] bf16: 71,303,168
  ushort* Yp  = Xg;                           // Ypair overlays Xg
  char* sm = ws + 893386752;
  int*   slot_token = (int*)(sm);
  float* slot_w     = (float*)(sm + 69632);
  int*   token_slot = (int*)(sm + 139264);
  int*   topk_idx   = (int*)(sm + 204800);
  float* topk_w     = (float*)(sm + 270336);
  int*   counts     = (int*)(sm + 335872);
  int*   cursors    = (int*)(sm + 335936);
  int*   offs       = (int*)(sm + 336000);

  hipMemsetAsync(counts, 0, 128, stream);
  hipMemsetAsync(slot_token, 0xFF, MAXROWS * 4, stream);

  router_kernel<<<dim3(T_TOK / 4), dim3(256), 0, stream>>>(x, gw, topk_idx, topk_w, counts);
  offsets_kernel<<<dim3(1), dim3(64), 0, stream>>>(counts, offs);
  scatter_kernel<<<dim3(T_TOK / 256), dim3(256), 0, stream>>>(
      topk_idx, topk_w, offs, cursors, slot_token, slot_w, token_slot);
  gather_kernel<<<dim3(MAXROWS), dim3(256), 0, stream>>>(x, slot_token, Xg);

  transpose_convert_kernel<<<dim3(FFN_ / 64, HID / 64, NE), dim3(256), 0, stream>>>(
      w1, w1t, HID, FFN_);
  transpose_convert_kernel<<<dim3(HID / 64, FFN_ / 64, NE), dim3(256), 0, stream>>>(
      w2, w2t, FFN_, HID);

  gemm8_kernel<0><<<dim3(FFN_ / BN2, MAXROWS / BM), dim3(512), 0, stream>>>(
      Xg, w1t, b1, Hb, nullptr, offs, HID, FFN_, FFN_ / BN2);
  gemm8_kernel<1><<<dim3(HID / BN2, MAXROWS / BM), dim3(512), 0, stream>>>(
      Hb, w2t, b2, Yp, slot_w, offs, FFN_, HID, HID / BN2);

  combine_kernel<<<dim3(T_TOK), dim3(256), 0, stream>>>(x, Yp, token_slot, out);
}

// Round 3
// 2036.354 us; speedup vs baseline: 1.2973x; 1.0997x over previous
//
#include <hip/hip_runtime.h>
#include <hip/hip_bf16.h>

#define T_TOK 8192
#define HID 2048
#define FFN_ 8192
#define NE 8
#define MAXR 18432   // 16384 + 8*256 padding (segments 256-aligned)

typedef __attribute__((ext_vector_type(8))) short bf16x8;
typedef __attribute__((ext_vector_type(4))) float f32x4;
typedef __attribute__((ext_vector_type(8))) unsigned short u16x8;

__device__ __forceinline__ unsigned short f2bf(float f) {
  unsigned int u = __float_as_uint(f);
  u += 0x7fffu + ((u >> 16) & 1u);   // RNE
  return (unsigned short)(u >> 16);
}
__device__ __forceinline__ float bf2f(unsigned short h) {
  return __uint_as_float(((unsigned int)h) << 16);
}

__device__ __forceinline__ void gload_lds16(const ushort* g, ushort* l) {
  __builtin_amdgcn_global_load_lds(
      (const __attribute__((address_space(1))) unsigned int*)g,
      (__attribute__((address_space(3))) unsigned int*)l, 16, 0, 0);
}

// ---------------- router: one wave per token ----------------
__global__ __launch_bounds__(256) void router_kernel(
    const float* __restrict__ x, const float* __restrict__ gw,
    int* __restrict__ topk_idx, float* __restrict__ topk_w, int* __restrict__ counts)
{
  int lane = threadIdx.x & 63;
  int w = threadIdx.x >> 6;
  int t = blockIdx.x * 4 + w;
  const float* xr = x + (size_t)t * HID;
  float acc[NE];
#pragma unroll
  for (int e = 0; e < NE; ++e) acc[e] = 0.f;
  for (int h = lane; h < HID; h += 64) {
    float xv = xr[h];
#pragma unroll
    for (int e = 0; e < NE; ++e) acc[e] = fmaf(xv, gw[e * HID + h], acc[e]);
  }
#pragma unroll
  for (int e = 0; e < NE; ++e) {
#pragma unroll
    for (int s = 32; s > 0; s >>= 1) acc[e] += __shfl_xor(acc[e], s);
  }
  if (lane == 0) {
    int i0 = 0; float v0 = acc[0];
#pragma unroll
    for (int e = 1; e < NE; ++e) { if (acc[e] > v0) { v0 = acc[e]; i0 = e; } }
    int i1 = -1; float v1 = -3.4e38f;
#pragma unroll
    for (int e = 0; e < NE; ++e) { if (e != i0 && acc[e] > v1) { v1 = acc[e]; i1 = e; } }
    float r = __expf(v1 - v0);
    float w0 = 1.f / (1.f + r);
    float w1 = r * w0;
    topk_idx[2 * t] = i0; topk_idx[2 * t + 1] = i1;
    topk_w[2 * t] = w0;   topk_w[2 * t + 1] = w1;
    atomicAdd(&counts[i0], 1);
    atomicAdd(&counts[i1], 1);
  }
}

__global__ void offsets_kernel(const int* __restrict__ counts, int* __restrict__ offs) {
  if (threadIdx.x == 0 && blockIdx.x == 0) {
    int o = 0;
#pragma unroll
    for (int e = 0; e < NE; ++e) { offs[e] = o; o += (counts[e] + 255) & ~255; }
    offs[NE] = o;
  }
}

__global__ __launch_bounds__(256) void scatter_kernel(
    const int* __restrict__ topk_idx, const float* __restrict__ topk_w,
    const int* __restrict__ offs, int* __restrict__ cursors,
    int* __restrict__ slot_token, float* __restrict__ slot_w, int* __restrict__ token_slot)
{
  int t = blockIdx.x * blockDim.x + threadIdx.x;
  if (t >= T_TOK) return;
#pragma unroll
  for (int k = 0; k < 2; ++k) {
    int e = topk_idx[2 * t + k];
    int pos = atomicAdd(&cursors[e], 1);
    int slot = offs[e] + pos;
    slot_token[slot] = t;
    slot_w[slot] = topk_w[2 * t + k];
    token_slot[2 * t + k] = slot;
  }
}

// gather token rows into bf16, one block per slot row
__global__ __launch_bounds__(256) void gather_kernel(
    const float* __restrict__ x, const int* __restrict__ slot_token, ushort* __restrict__ Xg)
{
  int row = blockIdx.x;
  int tok = slot_token[row];
  ushort* dst = Xg + (size_t)row * HID + threadIdx.x * 8;
  if (tok < 0) {
    u16x8 z = {0, 0, 0, 0, 0, 0, 0, 0};
    *(u16x8*)dst = z;
  } else {
    const float* s = x + (size_t)tok * HID + threadIdx.x * 8;
    float4 a = *(const float4*)s;
    float4 b = *(const float4*)(s + 4);
    u16x8 v;
    v[0] = f2bf(a.x); v[1] = f2bf(a.y); v[2] = f2bf(a.z); v[3] = f2bf(a.w);
    v[4] = f2bf(b.x); v[5] = f2bf(b.y); v[6] = f2bf(b.z); v[7] = f2bf(b.w);
    *(u16x8*)dst = v;
  }
}

// fp32 [E][R][C] -> bf16 [E][C][R]
__global__ __launch_bounds__(256) void transpose_convert_kernel(
    const float* __restrict__ src, ushort* __restrict__ dst, int R, int C)
{
  __shared__ float tile[64][65];
  int e = blockIdx.z;
  const float* s = src + (size_t)e * R * C;
  ushort* d = dst + (size_t)e * R * C;
  int r0 = blockIdx.y << 6, c0 = blockIdx.x << 6;
  int t = threadIdx.x;
#pragma unroll
  for (int i = 0; i < 4; ++i) {
    int idx = i * 256 + t;
    int row = idx >> 4;
    int c4 = (idx & 15) << 2;
    float4 v = *(const float4*)&s[(size_t)(r0 + row) * C + (c0 + c4)];
    tile[row][c4 + 0] = v.x; tile[row][c4 + 1] = v.y;
    tile[row][c4 + 2] = v.z; tile[row][c4 + 3] = v.w;
  }
  __syncthreads();
#pragma unroll
  for (int i = 0; i < 8; ++i) {
    int idx = (i * 256 + t) * 2;
    int orow = idx >> 6;
    int ocol = idx & 63;
    ushort2 p;
    p.x = f2bf(tile[ocol][orow]);
    p.y = f2bf(tile[ocol + 1][orow]);
    *(ushort2*)&d[(size_t)(c0 + orow) * R + (r0 + ocol)] = p;
  }
}

// ============ GEMM 256x256, BK=64, 8 waves, 8-phase schedule (m201 template) ============
// C[row][col] = A[row][:] . Bt[col][:]  (both K-contiguous)
// LDS per buffer (ushort): [A_first 8192][A_second 8192][B_first 8192][B_second 8192]
// A_first  = tile rows {0-63, 128-191}   (rows read in phases 1-2 by waves wr=0/1)
// A_second = tile rows {64-127, 192-255} (read in phases 3-4)
// B_first  = tile rows {wc*64+[0,32)}    (read in phases 1,3)
// B_second = tile rows {wc*64+[32,64)}   (read in phases 2,4)
// Within each 128x64 region: 16B chunk j of phys row p stored at chunk j^(p&7).
// global_load_lds writes LINEAR; source global addr pre-swizzled (rule 21).

#define WAIT_LGKM() do { asm volatile("s_waitcnt lgkmcnt(0)" ::: "memory"); \
                         __builtin_amdgcn_sched_barrier(0); } while (0)
#define WAIT_VM6()  do { asm volatile("s_waitcnt vmcnt(6)" ::: "memory");  \
                         __builtin_amdgcn_sched_barrier(0); } while (0)
#define WAIT_VM0()  do { asm volatile("s_waitcnt vmcnt(0)" ::: "memory");  \
                         __builtin_amdgcn_sched_barrier(0); } while (0)

#define STG_A(BUF, HALF, T) do {                                            \
    ushort* _d = lds + (BUF) * 32768 + (HALF) * 8192 + tid * 8;             \
    gload_lds16(sA0 + (size_t)(HALF) * 64 * K + (size_t)(T) * 64, _d);      \
    gload_lds16(sA1 + (size_t)(HALF) * 64 * K + (size_t)(T) * 64, _d + 4096); \
  } while (0)
#define STG_B(BUF, HALF, T) do {                                            \
    ushort* _d = lds + (BUF) * 32768 + 16384 + (HALF) * 8192 + tid * 8;     \
    gload_lds16(sB0 + (size_t)(HALF) * 32 * K + (size_t)(T) * 64, _d);      \
    gload_lds16(sB1 + (size_t)(HALF) * 32 * K + (size_t)(T) * 64, _d + 4096); \
  } while (0)

#define LDA(BUF, MQ) do {                                                   \
    _Pragma("unroll") for (int mm = 0; mm < 4; ++mm) {                      \
      const ushort* _p = lds + (BUF) * 32768 + (MQ) * 8192 + aoff + mm * 1024; \
      af[mm][0] = *(const bf16x8*)(_p + ck0);                               \
      af[mm][1] = *(const bf16x8*)(_p + ck1);                               \
    } } while (0)
#define LDB(BUF, NQ) do {                                                   \
    _Pragma("unroll") for (int nn = 0; nn < 2; ++nn) {                      \
      const ushort* _p = lds + (BUF) * 32768 + 16384 + (NQ) * 8192 + boff + nn * 1024; \
      bf[NQ][nn][0] = *(const bf16x8*)(_p + ck0);                           \
      bf[NQ][nn][1] = *(const bf16x8*)(_p + ck1);                           \
    } } while (0)

#define MFMA_Q(MQ, NQ) do {                                                 \
    _Pragma("unroll") for (int mm = 0; mm < 4; ++mm)                        \
    _Pragma("unroll") for (int nn = 0; nn < 2; ++nn) {                      \
      acc[(MQ)*4+mm][(NQ)*2+nn] = __builtin_amdgcn_mfma_f32_16x16x32_bf16(  \
          af[mm][0], bf[NQ][nn][0], acc[(MQ)*4+mm][(NQ)*2+nn], 0, 0, 0);    \
      acc[(MQ)*4+mm][(NQ)*2+nn] = __builtin_amdgcn_mfma_f32_16x16x32_bf16(  \
          af[mm][1], bf[NQ][nn][1], acc[(MQ)*4+mm][(NQ)*2+nn], 0, 0, 0);    \
    } } while (0)

#define PH_MFMA(MQ, NQ) do {                                                \
    __builtin_amdgcn_s_barrier();                                           \
    WAIT_LGKM();                                                            \
    __builtin_amdgcn_s_setprio(1);                                          \
    MFMA_Q(MQ, NQ);                                                         \
    __builtin_amdgcn_s_setprio(0);                                          \
    __builtin_amdgcn_sched_barrier(0);                                      \
  } while (0)

template <int EPI>
__global__ __launch_bounds__(512, 2) void gemm256_kernel(
    const ushort* __restrict__ A, const ushort* __restrict__ Bt,
    const float* __restrict__ bias, ushort* __restrict__ Cout,
    const float* __restrict__ slot_w, const int* __restrict__ offs,
    int K, int N, int gx)
{
  __shared__ ushort lds[65536];   // 128 KiB

  const int tid = threadIdx.x;
  int nwg = gridDim.x * gridDim.y;
  int wg = blockIdx.y * gridDim.x + blockIdx.x;
  int cpx = nwg >> 3;
  wg = (wg & 7) * cpx + (wg >> 3);            // T1: XCD swizzle (nwg % 8 == 0)
  int rb = wg / gx, cb = wg - rb * gx;

  int total = offs[NE];
  int row0 = rb * 256;
  if (row0 >= total) return;
  int e = 0;
#pragma unroll
  for (int i = 1; i < NE; ++i) e += (row0 >= offs[i]) ? 1 : 0;

  const ushort* Ag = A + (size_t)row0 * K;
  const ushort* Bg = Bt + ((size_t)e * N + (size_t)cb * 256) * K;

  // staging source (pre-swizzled); LDS dest linear: chunk c = l*512+tid
  const int pr0 = tid >> 3;                 // phys row, l=0 (0..63)
  const int pr1 = 64 + pr0;                 // phys row, l=1
  const int j0 = (tid & 7) ^ (pr0 & 7);
  const int j1 = (tid & 7) ^ (pr1 & 7);
  const int rA0 = pr0;                      // A map: (p>>6)*128 + (p&63)
  const int rA1 = 128 + pr0;
  const int rB0 = ((pr0 >> 5) << 6) + (pr0 & 31);   // B map: (p>>5)*64 + (p&31)
  const int rB1 = ((pr1 >> 5) << 6) + (pr1 & 31);
  const ushort* sA0 = Ag + (size_t)rA0 * K + j0 * 8;
  const ushort* sA1 = Ag + (size_t)rA1 * K + j1 * 8;
  const ushort* sB0 = Bg + (size_t)rB0 * K + j0 * 8;
  const ushort* sB1 = Bg + (size_t)rB1 * K + j1 * 8;

  // fragment read addressing
  const int lane = tid & 63;
  const int wid = tid >> 6;
  const int wr = wid >> 2, wc = wid & 3;    // wave grid 2(M) x 4(N)
  const int lrow = lane & 15, g = lane >> 4, x7 = lrow & 7;
  const int ck0 = (g ^ x7) * 8;             // kk=0 swizzled chunk (ushorts)
  const int ck1 = ((4 + g) ^ x7) * 8;       // kk=1
  const int aoff = (wr * 64 + lrow) * 64;   // phys-row offset within A region
  const int boff = (wc * 32 + lrow) * 64;   // within B region

  f32x4 acc[8][4] = {};
  bf16x8 af[4][2], bf[2][2][2];

  const int NT = K >> 6;
  const int NITER = NT >> 1;

  // prologue: tile0 full + tile1 {A_first,B_first,B_second}; wait tile0 landed
  STG_A(0, 0, 0); STG_A(0, 1, 0); STG_B(0, 0, 0); STG_B(0, 1, 0);
  STG_A(1, 0, 1); STG_B(1, 0, 1); STG_B(1, 1, 1);
  WAIT_VM6();
  __builtin_amdgcn_s_barrier();

  for (int it = 0; it < NITER; ++it) {
    const int tb = 2 * it + 1;
    const int tn0 = 2 * it + 2;
    const int tn1 = 2 * it + 3;
    const bool more0 = tn0 < NT;
    const bool more1 = tn1 < NT;

    // ph1: Q(0,0) of buf0 ; stage A_second(tb)->buf1
    LDA(0, 0); LDB(0, 0);
    STG_A(1, 1, tb);
    PH_MFMA(0, 0);
    __builtin_amdgcn_s_barrier();

    // ph2: Q(0,1) buf0 ; stage A_first(tn0)->buf0
    LDB(0, 1);
    if (more0) STG_A(0, 0, tn0);
    PH_MFMA(0, 1);
    __builtin_amdgcn_s_barrier();

    // ph3: Q(1,0) buf0 ; stage B_first(tn0)
    LDA(0, 1);
    if (more0) STG_B(0, 0, tn0);
    PH_MFMA(1, 0);
    __builtin_amdgcn_s_barrier();

    // ph4: Q(1,1) buf0 ; stage B_second(tn0); vmcnt gate for buf1 reads
    if (more0) STG_B(0, 1, tn0);
    PH_MFMA(1, 1);
    if (it + 1 < NITER) { WAIT_VM6(); } else { WAIT_VM0(); }
    __builtin_amdgcn_s_barrier();

    // ph5: Q(0,0) buf1 ; stage A_second(tn0)->buf0
    LDA(1, 0); LDB(1, 0);
    if (more0) STG_A(0, 1, tn0);
    PH_MFMA(0, 0);
    __builtin_amdgcn_s_barrier();

    // ph6: Q(0,1) buf1 ; stage A_first(tn1)->buf1
    LDB(1, 1);
    if (more1) STG_A(1, 0, tn1);
    PH_MFMA(0, 1);
    __builtin_amdgcn_s_barrier();

    // ph7: Q(1,0) buf1 ; stage B_first(tn1)
    LDA(1, 1);
    if (more1) STG_B(1, 0, tn1);
    PH_MFMA(1, 0);
    __builtin_amdgcn_s_barrier();

    // ph8: Q(1,1) buf1 ; stage B_second(tn1); vmcnt gate for next-iter buf0 reads
    if (more1) STG_B(1, 1, tn1);
    PH_MFMA(1, 1);
    if (more1) WAIT_VM6();
    __builtin_amdgcn_s_barrier();
  }

  // epilogue
  const int colb = cb * 256 + wc * 64;
  const int rowb = row0 + wr * 128;
#pragma unroll
  for (int n = 0; n < 4; ++n) {
    const int nq = n >> 1, nn = n & 1;
    const int gc = colb + nq * 32 + nn * 16 + lrow;
    const float bv = bias[(size_t)e * N + gc];
#pragma unroll
    for (int m = 0; m < 8; ++m) {
      const int mq = m >> 2, mm = m & 3;
      const int gr = rowb + mq * 64 + mm * 16 + g * 4;
#pragma unroll
      for (int i = 0; i < 4; ++i) {
        float v = acc[m][n][i] + bv;
        if (EPI == 0) {
          v = 0.5f * v * (1.f + erff(v * 0.70710678118654752f));
        } else {
          v *= slot_w[gr + i];
        }
        Cout[(size_t)(gr + i) * N + gc] = f2bf(v);
      }
    }
  }
}

// out = x + Y[slot0] + Y[slot1]
__global__ __launch_bounds__(256) void combine_kernel(
    const float* __restrict__ x, const ushort* __restrict__ Yp,
    const int* __restrict__ token_slot, float* __restrict__ out)
{
  int t = blockIdx.x;
  int s0 = token_slot[2 * t], s1 = token_slot[2 * t + 1];
  int c = threadIdx.x * 8;
  const float* xr = x + (size_t)t * HID + c;
  u16x8 y0 = *(const u16x8*)&Yp[(size_t)s0 * HID + c];
  u16x8 y1 = *(const u16x8*)&Yp[(size_t)s1 * HID + c];
  float4 xa = *(const float4*)xr;
  float4 xb = *(const float4*)(xr + 4);
  float4 oa, ob;
  oa.x = xa.x + bf2f(y0[0]) + bf2f(y1[0]);
  oa.y = xa.y + bf2f(y0[1]) + bf2f(y1[1]);
  oa.z = xa.z + bf2f(y0[2]) + bf2f(y1[2]);
  oa.w = xa.w + bf2f(y0[3]) + bf2f(y1[3]);
  ob.x = xb.x + bf2f(y0[4]) + bf2f(y1[4]);
  ob.y = xb.y + bf2f(y0[5]) + bf2f(y1[5]);
  ob.z = xb.z + bf2f(y0[6]) + bf2f(y1[6]);
  ob.w = xb.w + bf2f(y0[7]) + bf2f(y1[7]);
  float* orow = out + (size_t)t * HID + c;
  *(float4*)orow = oa;
  *(float4*)(orow + 4) = ob;
}

extern "C" void kernel_launch(void* const* d_in, const int* in_sizes, int n_in,
                              void* d_out, int out_size, void* d_ws, size_t ws_size,
                              hipStream_t stream)
{
  const float* x  = (const float*)d_in[0];
  const float* gw = (const float*)d_in[1];
  const float* w1 = (const float*)d_in[2];
  const float* b1 = (const float*)d_in[3];
  const float* w2 = (const float*)d_in[4];
  const float* b2 = (const float*)d_in[5];
  float* out = (float*)d_out;

  char* ws = (char*)d_ws;
  // wT holds w1t during gemm1, then is overwritten with w2t before gemm2.
  ushort* wT  = (ushort*)(ws + 0);            // [E][out][K] bf16: 268,435,456
  ushort* Hb  = (ushort*)(ws + 268435456);    // [MAXR][FFN] bf16: 301,989,888
  ushort* Xg  = (ushort*)(ws + 570425344);    // [MAXR][HID] bf16: 75,497,472
  ushort* Yp  = Xg;                           // Ypair overlays Xg
  char* sm = ws + 645922816;
  int*   slot_token = (int*)(sm);             // 73,728
  float* slot_w     = (float*)(sm + 73728);   // 73,728
  int*   token_slot = (int*)(sm + 147456);    // 65,536
  int*   topk_idx   = (int*)(sm + 212992);    // 65,536
  float* topk_w     = (float*)(sm + 278528);  // 65,536
  int*   counts     = (int*)(sm + 344064);    // 32
  int*   cursors    = (int*)(sm + 344096);    // 32
  int*   offs       = (int*)(sm + 344128);    // 36

  hipMemsetAsync(counts, 0, 64, stream);                 // counts + cursors
  hipMemsetAsync(slot_token, 0xFF, MAXR * 4, stream);    // -1 padding

  router_kernel<<<dim3(T_TOK / 4), dim3(256), 0, stream>>>(x, gw, topk_idx, topk_w, counts);
  offsets_kernel<<<dim3(1), dim3(64), 0, stream>>>(counts, offs);
  scatter_kernel<<<dim3(T_TOK / 256), dim3(256), 0, stream>>>(
      topk_idx, topk_w, offs, cursors, slot_token, slot_w, token_slot);
  gather_kernel<<<dim3(MAXR), dim3(256), 0, stream>>>(x, slot_token, Xg);

  // w1 fp32 [H][F] -> bf16 [F][H] per expert
  transpose_convert_kernel<<<dim3(FFN_ / 64, HID / 64, NE), dim3(256), 0, stream>>>(
      w1, wT, HID, FFN_);
  gemm256_kernel<0><<<dim3(FFN_ / 256, MAXR / 256), dim3(512), 0, stream>>>(
      Xg, wT, b1, Hb, nullptr, offs, HID, FFN_, FFN_ / 256);

  // w2 fp32 [F][H] -> bf16 [H][F] per expert (reuses wT)
  transpose_convert_kernel<<<dim3(HID / 64, FFN_ / 64, NE), dim3(256), 0, stream>>>(
      w2, wT, FFN_, HID);
  gemm256_kernel<1><<<dim3(HID / 256, MAXR / 256), dim3(512), 0, stream>>>(
      Hb, wT, b2, Yp, slot_w, offs, FFN_, HID, HID / 256);

  combine_kernel<<<dim3(T_TOK), dim3(256), 0, stream>>>(x, Yp, token_slot, out);
}